// Round 4
// baseline (318.244 us; speedup 1.0000x reference)
//
#include <hip/hip_runtime.h>
#include <stdint.h>

#define ET 128
#define ES 16
#define KSTEPS 3
#define ACC_STRIDE 258   // doubles per replica slot
#define ACC_USED 34      // [0]=sum_w [1]=sum_klw [2..17]=t_counts [18..33]=s_counts
#define MAX_REPL 64
#define NITER 3          // diagnostic: internal repeats into disjoint bank sets
#define B_OFF_DOUBLES (4u * 1024u * 1024u)   // kernel-B dummy region: 32MB into ws

__host__ __device__ inline void tf2x32(uint32_t k0, uint32_t k1,
                                       uint32_t& x0, uint32_t& x1) {
  uint32_t ks2 = k0 ^ k1 ^ 0x1BD11BDAu;
  x0 += k0; x1 += k1;
#define TF_ROT(r) { x0 += x1; x1 = (x1 << (r)) | (x1 >> (32 - (r))); x1 ^= x0; }
  TF_ROT(13) TF_ROT(15) TF_ROT(26) TF_ROT(6)
  x0 += k1;  x1 += ks2 + 1u;
  TF_ROT(17) TF_ROT(29) TF_ROT(16) TF_ROT(24)
  x0 += ks2; x1 += k0 + 2u;
  TF_ROT(13) TF_ROT(15) TF_ROT(26) TF_ROT(6)
  x0 += k0;  x1 += k1 + 3u;
  TF_ROT(17) TF_ROT(29) TF_ROT(16) TF_ROT(24)
  x0 += k1;  x1 += ks2 + 4u;
  TF_ROT(13) TF_ROT(15) TF_ROT(26) TF_ROT(6)
  x0 += ks2; x1 += k0 + 5u;
#undef TF_ROT
}

__device__ inline float unif01(uint32_t s0, uint32_t s1, uint32_t j) {
  uint32_t x0 = 0u, x1 = j;
  tf2x32(s0, s1, x0, x1);
  uint32_t bits = x0 ^ x1;
  float f = __uint_as_float((bits >> 9) | 0x3F800000u) - 1.0f;
  const float TINY = 1.17549435e-38f;
  return fmaxf(TINY, f + TINY);
}

__device__ inline float gumbelf(float u) { return -__logf(-__logf(u)); }

__device__ inline unsigned long long argkey(float v, int idx) {
  uint32_t b = __float_as_uint(v);
  uint32_t u = b ^ (0x80000000u | (uint32_t)((int32_t)b >> 31));
  return ((unsigned long long)u << 32) | (uint32_t)(255 - idx);
}

// DIAG=0: real kernel (cross-lane argmax).  DIAG=1: identical except ALL
// cross-lane DS ops (butterfly + broadcasts) removed; lane-local winner.
// Output of DIAG=1 is deterministic garbage into an unread ws region.
template <int DIAG>
__launch_bounds__(256)
__global__ void sample_kernel(const float* __restrict__ tg,
                              const float* __restrict__ sg,
                              const int* __restrict__ am,
                              double* __restrict__ accbase, int repl,
                              int set_stride, int niter,
                              uint32_t s00, uint32_t s01,
                              uint32_t s10, uint32_t s11,
                              uint32_t s20, uint32_t s21,
                              int N, int total_waves) {
  __shared__ float lds_t[ES], lds_s[ES];
  __shared__ float lds_w[4], lds_kl[4];

  const int wslot = threadIdx.x >> 6;
  const int wid = blockIdx.x * 4 + wslot;
  const int lane = threadIdx.x & 63;
  const float LN2 = 0.69314718055994530942f;

#pragma unroll 1
  for (int it = 0; it < niter; ++it) {
    double* acc = accbase + (size_t)it * set_stride;
    __syncthreads();
    if (threadIdx.x < ES) { lds_t[threadIdx.x] = 0.f; lds_s[threadIdx.x] = 0.f; }
    __syncthreads();

    float sum_w = 0.f, sum_kl = 0.f;

    for (int n = wid; n < N; n += total_waves) {
      const float* row = tg + (size_t)n * ET;
      float p0 = row[lane];
      float p1 = row[lane + 64];
      float vm = (float)am[n];

      const uint32_t j0 = (uint32_t)n * ET + (uint32_t)lane;
      float u00 = unif01(s00, s01, j0), u01 = unif01(s00, s01, j0 + 64u);
      float u10 = unif01(s10, s11, j0), u11 = unif01(s10, s11, j0 + 64u);
      float u20 = unif01(s20, s21, j0), u21 = unif01(s20, s21, j0 + 64u);
      float lp0 = __logf(p0), lp1 = __logf(p1);
      float b0[KSTEPS] = {gumbelf(u00) + lp0, gumbelf(u10) + lp0, gumbelf(u20) + lp0};
      float b1[KSTEPS] = {gumbelf(u01) + lp1, gumbelf(u11) + lp1, gumbelf(u21) + lp1};

      float c0 = 0.f, c1 = 0.f;
      float t = 1.0f;

#pragma unroll
      for (int k = 0; k < KSTEPS; ++k) {
        float v0 = fmaf(c0, -LN2, b0[k]);
        float v1 = fmaf(c1, -LN2, b1[k]);
        unsigned long long k0 = argkey(v0, lane);
        unsigned long long k1 = argkey(v1, lane + 64);
        unsigned long long key = (k1 > k0) ? k1 : k0;

        int bi;
        float w_abs;
        if constexpr (DIAG == 0) {
#pragma unroll
          for (int off = 32; off; off >>= 1) {
            unsigned long long ok = __shfl_xor(key, off);
            if (ok > key) key = ok;
          }
          bi = 255 - (int)(key & 0xFFu);
          float w0b = __shfl(p0, bi & 63);
          float w1b = __shfl(p1, bi & 63);
          w_abs = (bi < 64) ? w0b : w1b;
        } else {
          // lane-local "winner": same VALU shape, zero cross-lane traffic
          bi = 255 - (int)(key & 0xFFu);
          w_abs = (bi < 64) ? p0 : p1;
        }

        if (lane == 0) {
          float ws = w_abs * __frcp_rn(t) * vm;
          sum_w += ws;
          if ((bi & 7) == 0)
            sum_kl += -__logf(sg[(size_t)n * ES + ((bi >> 3) & 15)]) * ws;
          if (bi < ES) {
            atomicAdd(&lds_t[bi], ws);
            atomicAdd(&lds_s[bi], sg[(size_t)n * ES + bi] * vm);
          }
        }
        if (k < KSTEPS - 1) {
          if (lane == (bi & 63)) {
            if (bi < 64) { p0 *= 0.5f; c0 += 1.f; }
            else         { p1 *= 0.5f; c1 += 1.f; }
          }
          t -= 0.5f * w_abs;
        }
      }
    }

    if (lane == 0) { lds_w[wslot] = sum_w; lds_kl[wslot] = sum_kl; }
    __syncthreads();

    double* slot = acc + (size_t)(blockIdx.x % repl) * ACC_STRIDE;
    if (threadIdx.x == 0) {
      atomicAdd(&slot[0], (double)(lds_w[0] + lds_w[1] + lds_w[2] + lds_w[3]));
      atomicAdd(&slot[1], (double)(lds_kl[0] + lds_kl[1] + lds_kl[2] + lds_kl[3]));
    }
    if (threadIdx.x < ES) {
      atomicAdd(&slot[2 + threadIdx.x], (double)lds_t[threadIdx.x]);
      atomicAdd(&slot[2 + ES + threadIdx.x], (double)lds_s[threadIdx.x]);
    }
  }
}

__global__ void finalize_kernel(const double* __restrict__ acc, int repl,
                                float* __restrict__ out) {
  __shared__ double tot[ACC_USED];
  const int tid = threadIdx.x;
  if (tid < ACC_USED) {
    double s = 0.0;
    for (int r = 0; r < repl; ++r) s += acc[(size_t)r * ACC_STRIDE + tid];
    tot[tid] = s;
  }
  __syncthreads();
  if (tid != 0) return;

  const double EPSD = 1e-8;
  double feat = tot[1] / fmax(tot[0], EPSD);

  double tsum = 0.0, ssum = 0.0;
  for (int i = 0; i < ES; ++i) { tsum += tot[2 + i]; ssum += tot[2 + ES + i]; }
  double ta2 = 0.0, sa2 = 0.0;
  for (int i = 0; i < ES; ++i) {
    ta2 += tot[2 + i] / tsum + EPSD;
    sa2 += tot[2 + ES + i] / ssum + EPSD;
  }
  ta2 += (ET - ES) * EPSD;
  sa2 += (ET - ES) * EPSD;
  double cov = 0.0;
  for (int i = 0; i < ES; ++i) {
    double ta = (tot[2 + i] / tsum + EPSD) / ta2;
    double sa = (tot[2 + ES + i] / ssum + EPSD) / sa2;
    cov += ta * (log(ta) - log(sa));
  }
  {
    double ta0 = EPSD / ta2, sa0 = EPSD / sa2;
    cov += (double)(ET - ES) * ta0 * (log(ta0) - log(sa0));
  }
  cov /= (double)ET;
  out[0] = (float)(feat + 0.5 * cov);
}

extern "C" void kernel_launch(void* const* d_in, const int* in_sizes, int n_in,
                              void* d_out, int out_size, void* d_ws, size_t ws_size,
                              hipStream_t stream) {
  const float* tg = (const float*)d_in[0];
  const float* sg = (const float*)d_in[1];
  const int*   am = (const int*)d_in[4];
  const int N = in_sizes[4];  // B*S tokens

  // key chain: key = jax.random.key(42); per step foldlike split (partitionable)
  uint32_t key0 = 0u, key1 = 42u;
  uint32_t subs[KSTEPS][2];
  for (int k = 0; k < KSTEPS; ++k) {
    uint32_t a0 = 0u, a1 = 0u; tf2x32(key0, key1, a0, a1);
    uint32_t b0 = 0u, b1 = 1u; tf2x32(key0, key1, b0, b1);
    subs[k][0] = b0; subs[k][1] = b1;
    key0 = a0; key1 = a1;
  }

  int repl = MAX_REPL;
  const int set_stride = repl * ACC_STRIDE;                  // doubles per bank set
  const size_t a_bytes = (size_t)NITER * set_stride * sizeof(double);
  const size_t b_need = ((size_t)B_OFF_DOUBLES + (size_t)NITER * set_stride) * sizeof(double);
  const int run_diag = (ws_size >= b_need) ? 1 : 0;
  (void)a_bytes;

  double* acc = (double*)d_ws;
  // zero only bank set 0 (the one finalize reads)
  hipMemsetAsync(d_ws, 0, (size_t)set_stride * sizeof(double), stream);

  int blocks = 2048;
  if (blocks * 4 > N) blocks = (N + 3) / 4;
  const int total_waves = blocks * 4;

  sample_kernel<0><<<blocks, 256, 0, stream>>>(
      tg, sg, am, acc, repl, set_stride, NITER,
      subs[0][0], subs[0][1], subs[1][0], subs[1][1], subs[2][0], subs[2][1],
      N, total_waves);
  if (run_diag) {
    sample_kernel<1><<<blocks, 256, 0, stream>>>(
        tg, sg, am, acc + B_OFF_DOUBLES, repl, set_stride, NITER,
        subs[0][0], subs[0][1], subs[1][0], subs[1][1], subs[2][0], subs[2][1],
        N, total_waves);
  }
  finalize_kernel<<<1, 64, 0, stream>>>(acc, repl, (float*)d_out);
}

// Round 5
// 83.266 us; speedup vs baseline: 3.8220x; 3.8220x over previous
//
#include <hip/hip_runtime.h>
#include <stdint.h>

#define ET 128
#define ES 16
#define KSTEPS 3
#define ACC_STRIDE 258   // doubles per replica slot
#define ACC_USED 34      // [0]=sum_w [1]=sum_klw [2..17]=t_counts [18..33]=s_counts
#define MAX_REPL 64

__host__ __device__ inline void tf2x32(uint32_t k0, uint32_t k1,
                                       uint32_t& x0, uint32_t& x1) {
  uint32_t ks2 = k0 ^ k1 ^ 0x1BD11BDAu;
  x0 += k0; x1 += k1;
#define TF_ROT(r) { x0 += x1; x1 = (x1 << (r)) | (x1 >> (32 - (r))); x1 ^= x0; }
  TF_ROT(13) TF_ROT(15) TF_ROT(26) TF_ROT(6)
  x0 += k1;  x1 += ks2 + 1u;
  TF_ROT(17) TF_ROT(29) TF_ROT(16) TF_ROT(24)
  x0 += ks2; x1 += k0 + 2u;
  TF_ROT(13) TF_ROT(15) TF_ROT(26) TF_ROT(6)
  x0 += k0;  x1 += k1 + 3u;
  TF_ROT(17) TF_ROT(29) TF_ROT(16) TF_ROT(24)
  x0 += k1;  x1 += ks2 + 4u;
  TF_ROT(13) TF_ROT(15) TF_ROT(26) TF_ROT(6)
  x0 += ks2; x1 += k0 + 5u;
#undef TF_ROT
}

__device__ inline float unif01(uint32_t s0, uint32_t s1, uint32_t j) {
  uint32_t x0 = 0u, x1 = j;
  tf2x32(s0, s1, x0, x1);
  uint32_t bits = x0 ^ x1;
  float f = __uint_as_float((bits >> 9) | 0x3F800000u) - 1.0f;
  const float TINY = 1.17549435e-38f;
  return fmaxf(TINY, f + TINY);
}

__device__ inline float gumbelf(float u) { return -__logf(-__logf(u)); }

__device__ inline unsigned long long argkey(float v, int idx) {
  uint32_t b = __float_as_uint(v);
  uint32_t u = b ^ (0x80000000u | (uint32_t)((int32_t)b >> 31));
  return ((unsigned long long)u << 32) | (uint32_t)(255 - idx);
}

__launch_bounds__(256)
__global__ void sample_kernel(const float* __restrict__ tg,
                              const float* __restrict__ sg,
                              const int* __restrict__ am,
                              double* __restrict__ acc, int repl,
                              uint32_t s00, uint32_t s01,
                              uint32_t s10, uint32_t s11,
                              uint32_t s20, uint32_t s21,
                              int N, int total_waves) {
  __shared__ float lds_t[ES], lds_s[ES];
  __shared__ float lds_w[4], lds_kl[4];
  if (threadIdx.x < ES) { lds_t[threadIdx.x] = 0.f; lds_s[threadIdx.x] = 0.f; }
  __syncthreads();

  const int wslot = threadIdx.x >> 6;
  const int wid = blockIdx.x * 4 + wslot;
  const int lane = threadIdx.x & 63;
  const float LN2 = 0.69314718055994530942f;

  float sum_w = 0.f, sum_kl = 0.f;

  // two adjacent tokens per wave-iteration, fully interleaved pipelines
  for (int base = wid * 2; base < N; base += total_waves * 2) {
    const int nA = base;
    const int nB = base + 1;
    const int nBc = (nB < N) ? nB : (N - 1);

    // ---- issue ALL global loads up front (one vmcnt wait, hidden by threefry) ----
    const float* rowA = tg + (size_t)nA * ET;
    const float* rowB = tg + (size_t)nBc * ET;
    float pA0 = rowA[lane], pA1 = rowA[lane + 64];
    float pB0 = rowB[lane], pB1 = rowB[lane + 64];
    float sgA = (lane < ES) ? sg[(size_t)nA * ES + lane] : 0.f;   // whole sg row in regs
    float sgB = (lane < ES) ? sg[(size_t)nBc * ES + lane] : 0.f;
    float vmA = (float)am[nA];
    float vmB = (nB < N) ? (float)am[nBc] : 0.f;

    // ---- 12 independent threefry streams ----
    const uint32_t jA = (uint32_t)nA * ET + (uint32_t)lane;
    const uint32_t jB = (uint32_t)nBc * ET + (uint32_t)lane;
    float uA00 = unif01(s00, s01, jA), uA01 = unif01(s00, s01, jA + 64u);
    float uA10 = unif01(s10, s11, jA), uA11 = unif01(s10, s11, jA + 64u);
    float uA20 = unif01(s20, s21, jA), uA21 = unif01(s20, s21, jA + 64u);
    float uB00 = unif01(s00, s01, jB), uB01 = unif01(s00, s01, jB + 64u);
    float uB10 = unif01(s10, s11, jB), uB11 = unif01(s10, s11, jB + 64u);
    float uB20 = unif01(s20, s21, jB), uB21 = unif01(s20, s21, jB + 64u);

    float lpA0 = __logf(pA0), lpA1 = __logf(pA1);
    float lpB0 = __logf(pB0), lpB1 = __logf(pB1);
    float bA0[KSTEPS] = {gumbelf(uA00) + lpA0, gumbelf(uA10) + lpA0, gumbelf(uA20) + lpA0};
    float bA1[KSTEPS] = {gumbelf(uA01) + lpA1, gumbelf(uA11) + lpA1, gumbelf(uA21) + lpA1};
    float bB0[KSTEPS] = {gumbelf(uB00) + lpB0, gumbelf(uB10) + lpB0, gumbelf(uB20) + lpB0};
    float bB1[KSTEPS] = {gumbelf(uB01) + lpB1, gumbelf(uB11) + lpB1, gumbelf(uB21) + lpB1};

    float cA0 = 0.f, cA1 = 0.f, tA = 1.0f;
    float cB0 = 0.f, cB1 = 0.f, tB = 1.0f;

#pragma unroll
    for (int k = 0; k < KSTEPS; ++k) {
      float vA0 = fmaf(cA0, -LN2, bA0[k]);
      float vA1 = fmaf(cA1, -LN2, bA1[k]);
      float vB0 = fmaf(cB0, -LN2, bB0[k]);
      float vB1 = fmaf(cB1, -LN2, bB1[k]);
      unsigned long long keyA, keyB;
      { unsigned long long a = argkey(vA0, lane), b = argkey(vA1, lane + 64);
        keyA = (b > a) ? b : a; }
      { unsigned long long a = argkey(vB0, lane), b = argkey(vB1, lane + 64);
        keyB = (b > a) ? b : a; }
#pragma unroll
      for (int off = 32; off; off >>= 1) {
        unsigned long long oA = __shfl_xor(keyA, off);
        unsigned long long oB = __shfl_xor(keyB, off);
        if (oA > keyA) keyA = oA;
        if (oB > keyB) keyB = oB;
      }
      const int biA = 255 - (int)(keyA & 0xFFu);
      const int biB = 255 - (int)(keyB & 0xFFu);

      // wave-wide shuffles (bi is uniform): winner prob + sg values from regs
      float wA0 = __shfl(pA0, biA & 63), wA1 = __shfl(pA1, biA & 63);
      float wB0 = __shfl(pB0, biB & 63), wB1 = __shfl(pB1, biB & 63);
      float wAabs = (biA < 64) ? wA0 : wA1;
      float wBabs = (biB < 64) ? wB0 : wB1;
      float klA = __shfl(sgA, (biA >> 3) & 15);
      float klB = __shfl(sgB, (biB >> 3) & 15);
      float cvA = __shfl(sgA, biA & 15);
      float cvB = __shfl(sgB, biB & 15);

      if (lane == 0) {
        float wsA = wAabs * __frcp_rn(tA) * vmA;
        float wsB = wBabs * __frcp_rn(tB) * vmB;
        sum_w += wsA + wsB;
        if ((biA & 7) == 0) sum_kl += -__logf(klA) * wsA;
        if ((biB & 7) == 0) sum_kl += -__logf(klB) * wsB;
        if (biA < ES) {
          atomicAdd(&lds_t[biA], wsA);
          atomicAdd(&lds_s[biA], cvA * vmA);
        }
        if (biB < ES) {
          atomicAdd(&lds_t[biB], wsB);
          atomicAdd(&lds_s[biB], cvB * vmB);
        }
      }
      if (k < KSTEPS - 1) {
        if (lane == (biA & 63)) {
          if (biA < 64) { pA0 *= 0.5f; cA0 += 1.f; }
          else          { pA1 *= 0.5f; cA1 += 1.f; }
        }
        if (lane == (biB & 63)) {
          if (biB < 64) { pB0 *= 0.5f; cB0 += 1.f; }
          else          { pB1 *= 0.5f; cB1 += 1.f; }
        }
        tA -= 0.5f * wAabs;
        tB -= 0.5f * wBabs;
      }
    }
  }

  if (lane == 0) { lds_w[wslot] = sum_w; lds_kl[wslot] = sum_kl; }
  __syncthreads();

  double* slot = acc + (size_t)(blockIdx.x % repl) * ACC_STRIDE;
  if (threadIdx.x == 0) {
    atomicAdd(&slot[0], (double)(lds_w[0] + lds_w[1] + lds_w[2] + lds_w[3]));
    atomicAdd(&slot[1], (double)(lds_kl[0] + lds_kl[1] + lds_kl[2] + lds_kl[3]));
  }
  if (threadIdx.x < ES) {
    atomicAdd(&slot[2 + threadIdx.x], (double)lds_t[threadIdx.x]);
    atomicAdd(&slot[2 + ES + threadIdx.x], (double)lds_s[threadIdx.x]);
  }
}

__global__ void finalize_kernel(const double* __restrict__ acc, int repl,
                                float* __restrict__ out) {
  __shared__ double tot[ACC_USED];
  const int tid = threadIdx.x;
  if (tid < ACC_USED) {
    double s = 0.0;
    for (int r = 0; r < repl; ++r) s += acc[(size_t)r * ACC_STRIDE + tid];
    tot[tid] = s;
  }
  __syncthreads();
  if (tid != 0) return;

  const double EPSD = 1e-8;
  double feat = tot[1] / fmax(tot[0], EPSD);

  double tsum = 0.0, ssum = 0.0;
  for (int i = 0; i < ES; ++i) { tsum += tot[2 + i]; ssum += tot[2 + ES + i]; }
  double ta2 = 0.0, sa2 = 0.0;
  for (int i = 0; i < ES; ++i) {
    ta2 += tot[2 + i] / tsum + EPSD;
    sa2 += tot[2 + ES + i] / ssum + EPSD;
  }
  ta2 += (ET - ES) * EPSD;
  sa2 += (ET - ES) * EPSD;
  double cov = 0.0;
  for (int i = 0; i < ES; ++i) {
    double ta = (tot[2 + i] / tsum + EPSD) / ta2;
    double sa = (tot[2 + ES + i] / ssum + EPSD) / sa2;
    cov += ta * (log(ta) - log(sa));
  }
  {
    double ta0 = EPSD / ta2, sa0 = EPSD / sa2;
    cov += (double)(ET - ES) * ta0 * (log(ta0) - log(sa0));
  }
  cov /= (double)ET;
  out[0] = (float)(feat + 0.5 * cov);
}

extern "C" void kernel_launch(void* const* d_in, const int* in_sizes, int n_in,
                              void* d_out, int out_size, void* d_ws, size_t ws_size,
                              hipStream_t stream) {
  const float* tg = (const float*)d_in[0];
  const float* sg = (const float*)d_in[1];
  const int*   am = (const int*)d_in[4];
  const int N = in_sizes[4];  // B*S tokens

  // key chain: key = jax.random.key(42); per step foldlike split (partitionable)
  uint32_t key0 = 0u, key1 = 42u;
  uint32_t subs[KSTEPS][2];
  for (int k = 0; k < KSTEPS; ++k) {
    uint32_t a0 = 0u, a1 = 0u; tf2x32(key0, key1, a0, a1);  // new key
    uint32_t b0 = 0u, b1 = 1u; tf2x32(key0, key1, b0, b1);  // subkey
    subs[k][0] = b0; subs[k][1] = b1;
    key0 = a0; key1 = a1;
  }

  int repl = (int)(ws_size / (ACC_STRIDE * sizeof(double)));
  if (repl > MAX_REPL) repl = MAX_REPL;
  if (repl < 1) repl = 1;

  double* acc = (double*)d_ws;
  hipMemsetAsync(d_ws, 0, (size_t)repl * ACC_STRIDE * sizeof(double), stream);

  int blocks = 2048;
  if (blocks * 8 > N) blocks = (N + 7) / 8;   // 4 waves/block, 2 tokens/wave-iter
  const int total_waves = blocks * 4;

  sample_kernel<<<blocks, 256, 0, stream>>>(
      tg, sg, am, acc, repl,
      subs[0][0], subs[0][1], subs[1][0], subs[1][1], subs[2][0], subs[2][1],
      N, total_waves);
  finalize_kernel<<<1, 64, 0, stream>>>(acc, repl, (float*)d_out);
}

// Round 6
// 60.672 us; speedup vs baseline: 5.2453x; 1.3724x over previous
//
#include <hip/hip_runtime.h>
#include <stdint.h>

#define ET 128
#define ES 16
#define ACC_STRIDE 258   // doubles per replica slot
#define ACC_USED 34      // [0]=sum_w [1]=sum_klw [2..17]=t_counts [18..33]=s_counts
#define MAX_REPL 64

__host__ __device__ inline void tf2x32(uint32_t k0, uint32_t k1,
                                       uint32_t& x0, uint32_t& x1) {
  uint32_t ks2 = k0 ^ k1 ^ 0x1BD11BDAu;
  x0 += k0; x1 += k1;
#define TF_ROT(r) { x0 += x1; x1 = (x1 << (r)) | (x1 >> (32 - (r))); x1 ^= x0; }
  TF_ROT(13) TF_ROT(15) TF_ROT(26) TF_ROT(6)
  x0 += k1;  x1 += ks2 + 1u;
  TF_ROT(17) TF_ROT(29) TF_ROT(16) TF_ROT(24)
  x0 += ks2; x1 += k0 + 2u;
  TF_ROT(13) TF_ROT(15) TF_ROT(26) TF_ROT(6)
  x0 += k0;  x1 += k1 + 3u;
  TF_ROT(17) TF_ROT(29) TF_ROT(16) TF_ROT(24)
  x0 += k1;  x1 += ks2 + 4u;
  TF_ROT(13) TF_ROT(15) TF_ROT(26) TF_ROT(6)
  x0 += ks2; x1 += k0 + 5u;
#undef TF_ROT
}

// partitionable threefry: uniform(0,1) for flat index j under subkey s
__device__ inline float unif01(uint32_t s0, uint32_t s1, uint32_t j) {
  uint32_t x0 = 0u, x1 = j;
  tf2x32(s0, s1, x0, x1);
  uint32_t bits = x0 ^ x1;
  float f = __uint_as_float((bits >> 9) | 0x3F800000u) - 1.0f;
  const float TINY = 1.17549435e-38f;
  return fmaxf(TINY, f + TINY);
}

// 16 lanes per token, 8 experts per lane, 4 tokens per wave.
// Winner = argmin_e( -log(u_e) / p_e )  (exponential race == gumbel argmax).
// Scores are strictly positive => raw f32 bits are order-preserving; pack
// (bits<<32)|expert_idx into u64 and min-reduce => lowest-index tie-break.
__launch_bounds__(256)
__global__ void sample_kernel(const float* __restrict__ tg,
                              const float* __restrict__ sg,
                              const int* __restrict__ am,
                              double* __restrict__ acc, int repl,
                              uint32_t s00, uint32_t s01,
                              uint32_t s10, uint32_t s11,
                              uint32_t s20, uint32_t s21,
                              int N, int total_waves) {
  __shared__ float lds_t[ES], lds_s[ES];
  __shared__ float lds_w[4], lds_kl[4];
  if (threadIdx.x < ES) { lds_t[threadIdx.x] = 0.f; lds_s[threadIdx.x] = 0.f; }
  __syncthreads();

  const int wslot = threadIdx.x >> 6;
  const int wid = blockIdx.x * 4 + wslot;
  const int lane = threadIdx.x & 63;
  const int gl = lane & 15;          // lane within 16-lane token group
  const int gbase = lane & 0x30;     // first lane of this group

  float sum_w = 0.f, sum_kl = 0.f;

  for (int base = wid * 4; base < N; base += total_waves * 4) {
    const int nr = base + (lane >> 4);
    const int ok = (nr < N);
    const int n = ok ? nr : (N - 1);

    const float* row = tg + (size_t)n * ET + gl * 8;
    float4 pa = *(const float4*)row;
    float4 pb = *(const float4*)(row + 4);
    float p0 = pa.x, p1 = pa.y, p2 = pa.z, p3 = pa.w;
    float p4 = pb.x, p5 = pb.y, p6 = pb.z, p7 = pb.w;
    float sgv = sg[(size_t)n * ES + gl];         // this token's sg row, lane-cyclic
    float vm = ok ? (float)am[n] : 0.f;

    float i0 = __frcp_rn(p0), i1 = __frcp_rn(p1), i2 = __frcp_rn(p2), i3 = __frcp_rn(p3);
    float i4 = __frcp_rn(p4), i5 = __frcp_rn(p5), i6 = __frcp_rn(p6), i7 = __frcp_rn(p7);

    float t = 1.0f;                               // running norm of damped probs
    const uint32_t jb = (uint32_t)n * ET + (uint32_t)(gl * 8);
    const int ebase = gl * 8;

#define STEP(KA, KB, LAST)                                                      \
    {                                                                           \
      float e0 = -__logf(unif01(KA, KB, jb + 0u)) * i0;                         \
      float e1 = -__logf(unif01(KA, KB, jb + 1u)) * i1;                         \
      float e2 = -__logf(unif01(KA, KB, jb + 2u)) * i2;                         \
      float e3 = -__logf(unif01(KA, KB, jb + 3u)) * i3;                         \
      float e4 = -__logf(unif01(KA, KB, jb + 4u)) * i4;                         \
      float e5 = -__logf(unif01(KA, KB, jb + 5u)) * i5;                         \
      float e6 = -__logf(unif01(KA, KB, jb + 6u)) * i6;                         \
      float e7 = -__logf(unif01(KA, KB, jb + 7u)) * i7;                         \
      unsigned long long key, ko;                                               \
      key = ((unsigned long long)__float_as_uint(e0) << 32) | (uint32_t)(ebase + 0); \
      ko  = ((unsigned long long)__float_as_uint(e1) << 32) | (uint32_t)(ebase + 1); \
      if (ko < key) key = ko;                                                   \
      ko  = ((unsigned long long)__float_as_uint(e2) << 32) | (uint32_t)(ebase + 2); \
      if (ko < key) key = ko;                                                   \
      ko  = ((unsigned long long)__float_as_uint(e3) << 32) | (uint32_t)(ebase + 3); \
      if (ko < key) key = ko;                                                   \
      ko  = ((unsigned long long)__float_as_uint(e4) << 32) | (uint32_t)(ebase + 4); \
      if (ko < key) key = ko;                                                   \
      ko  = ((unsigned long long)__float_as_uint(e5) << 32) | (uint32_t)(ebase + 5); \
      if (ko < key) key = ko;                                                   \
      ko  = ((unsigned long long)__float_as_uint(e6) << 32) | (uint32_t)(ebase + 6); \
      if (ko < key) key = ko;                                                   \
      ko  = ((unsigned long long)__float_as_uint(e7) << 32) | (uint32_t)(ebase + 7); \
      if (ko < key) key = ko;                                                   \
      ko = __shfl_xor(key, 1); if (ko < key) key = ko;                          \
      ko = __shfl_xor(key, 2); if (ko < key) key = ko;                          \
      ko = __shfl_xor(key, 4); if (ko < key) key = ko;                          \
      ko = __shfl_xor(key, 8); if (ko < key) key = ko;                          \
      const int bi = (int)(key & 0xFFu);      /* winning teacher expert */      \
      const int wl = bi >> 3, wslt = bi & 7;                                    \
      float pw = p0;                                                            \
      pw = (wslt == 1) ? p1 : pw; pw = (wslt == 2) ? p2 : pw;                   \
      pw = (wslt == 3) ? p3 : pw; pw = (wslt == 4) ? p4 : pw;                   \
      pw = (wslt == 5) ? p5 : pw; pw = (wslt == 6) ? p6 : pw;                   \
      pw = (wslt == 7) ? p7 : pw;                                               \
      float w_abs = __shfl(pw, gbase | wl);    /* damped prob of winner */      \
      float sgkl = __shfl(sgv, gbase | wl);    /* sg[bi>>3] (wl == bi>>3) */    \
      float sgcv = __shfl(sgv, gbase | (bi & 15));                              \
      float wsv = w_abs * __frcp_rn(t) * vm;   /* renormalized weight */        \
      const bool lead = (gl == 0);                                              \
      sum_w += lead ? wsv : 0.f;                                                \
      float klt = ((bi & 7) == 0) ? (-__logf(sgkl)) * wsv : 0.f;                \
      sum_kl += lead ? klt : 0.f;                                               \
      if (lead && bi < ES) {                                                    \
        atomicAdd(&lds_t[bi], wsv);                                             \
        atomicAdd(&lds_s[bi], sgcv * vm);                                       \
      }                                                                         \
      if (!(LAST)) {                                                            \
        const bool mt = (gl == wl);                                             \
        p0 = (mt && wslt == 0) ? p0 * 0.5f : p0;  i0 = (mt && wslt == 0) ? i0 * 2.0f : i0; \
        p1 = (mt && wslt == 1) ? p1 * 0.5f : p1;  i1 = (mt && wslt == 1) ? i1 * 2.0f : i1; \
        p2 = (mt && wslt == 2) ? p2 * 0.5f : p2;  i2 = (mt && wslt == 2) ? i2 * 2.0f : i2; \
        p3 = (mt && wslt == 3) ? p3 * 0.5f : p3;  i3 = (mt && wslt == 3) ? i3 * 2.0f : i3; \
        p4 = (mt && wslt == 4) ? p4 * 0.5f : p4;  i4 = (mt && wslt == 4) ? i4 * 2.0f : i4; \
        p5 = (mt && wslt == 5) ? p5 * 0.5f : p5;  i5 = (mt && wslt == 5) ? i5 * 2.0f : i5; \
        p6 = (mt && wslt == 6) ? p6 * 0.5f : p6;  i6 = (mt && wslt == 6) ? i6 * 2.0f : i6; \
        p7 = (mt && wslt == 7) ? p7 * 0.5f : p7;  i7 = (mt && wslt == 7) ? i7 * 2.0f : i7; \
        t -= 0.5f * w_abs;                                                      \
      }                                                                         \
    }

    STEP(s00, s01, 0)
    STEP(s10, s11, 0)
    STEP(s20, s21, 1)
#undef STEP
  }

#pragma unroll
  for (int off = 32; off; off >>= 1) {
    sum_w += __shfl_xor(sum_w, off);
    sum_kl += __shfl_xor(sum_kl, off);
  }
  if (lane == 0) { lds_w[wslot] = sum_w; lds_kl[wslot] = sum_kl; }
  __syncthreads();

  double* slot = acc + (size_t)(blockIdx.x % repl) * ACC_STRIDE;
  if (threadIdx.x == 0) {
    atomicAdd(&slot[0], (double)(lds_w[0] + lds_w[1] + lds_w[2] + lds_w[3]));
    atomicAdd(&slot[1], (double)(lds_kl[0] + lds_kl[1] + lds_kl[2] + lds_kl[3]));
  }
  if (threadIdx.x < ES) {
    atomicAdd(&slot[2 + threadIdx.x], (double)lds_t[threadIdx.x]);
    atomicAdd(&slot[2 + ES + threadIdx.x], (double)lds_s[threadIdx.x]);
  }
}

__global__ void finalize_kernel(const double* __restrict__ acc, int repl,
                                float* __restrict__ out) {
  __shared__ double tot[ACC_USED];
  const int tid = threadIdx.x;
  if (tid < ACC_USED) {
    double s = 0.0;
    for (int r = 0; r < repl; ++r) s += acc[(size_t)r * ACC_STRIDE + tid];
    tot[tid] = s;
  }
  __syncthreads();

  const double EPSD = 1e-8;
  // lanes 0..15 own one bin each; lanes >=16 carry zeros (masked at the end)
  double tv = (tid < ES) ? tot[2 + tid] : 0.0;
  double sv = (tid < ES) ? tot[2 + ES + tid] : 0.0;
  double tsum = tv, ssum = sv;
#pragma unroll
  for (int off = 8; off; off >>= 1) {
    tsum += __shfl_xor(tsum, off);
    ssum += __shfl_xor(ssum, off);
  }
  double ta = tv / tsum + EPSD;   // NaN on lanes>=16, masked below
  double sa = sv / ssum + EPSD;
  double ta2 = (tid < ES) ? ta : 0.0;
  double sa2 = (tid < ES) ? sa : 0.0;
#pragma unroll
  for (int off = 8; off; off >>= 1) {
    ta2 += __shfl_xor(ta2, off);
    sa2 += __shfl_xor(sa2, off);
  }
  ta2 += (double)(ET - ES) * EPSD;   // 112 zero bins contribute EPS each
  sa2 += (double)(ET - ES) * EPSD;
  double tn = ta / ta2, sn = sa / sa2;
  double ci = (tid < ES) ? tn * (log(tn) - log(sn)) : 0.0;
#pragma unroll
  for (int off = 8; off; off >>= 1) ci += __shfl_xor(ci, off);

  if (tid == 0) {
    double ta0 = EPSD / ta2, sa0 = EPSD / sa2;
    double cov = ci + (double)(ET - ES) * ta0 * (log(ta0) - log(sa0));
    cov /= (double)ET;
    double feat = tot[1] / fmax(tot[0], EPSD);
    out[0] = (float)(feat + 0.5 * cov);
  }
}

extern "C" void kernel_launch(void* const* d_in, const int* in_sizes, int n_in,
                              void* d_out, int out_size, void* d_ws, size_t ws_size,
                              hipStream_t stream) {
  const float* tg = (const float*)d_in[0];
  const float* sg = (const float*)d_in[1];
  const int*   am = (const int*)d_in[4];
  const int N = in_sizes[4];  // B*S tokens

  // key chain: key = jax.random.key(42); per step foldlike split (partitionable)
  uint32_t key0 = 0u, key1 = 42u;
  uint32_t subs[3][2];
  for (int k = 0; k < 3; ++k) {
    uint32_t a0 = 0u, a1 = 0u; tf2x32(key0, key1, a0, a1);  // new key
    uint32_t b0 = 0u, b1 = 1u; tf2x32(key0, key1, b0, b1);  // subkey
    subs[k][0] = b0; subs[k][1] = b1;
    key0 = a0; key1 = a1;
  }

  int repl = (int)(ws_size / (ACC_STRIDE * sizeof(double)));
  if (repl > MAX_REPL) repl = MAX_REPL;
  if (repl < 1) repl = 1;

  double* acc = (double*)d_ws;
  hipMemsetAsync(d_ws, 0, (size_t)repl * ACC_STRIDE * sizeof(double), stream);

  // 4 waves/block, 4 tokens per wave-iteration => 16 tokens per block-iteration
  int blocks = (N + 15) / 16;
  if (blocks > 2048) blocks = 2048;
  const int total_waves = blocks * 4;

  sample_kernel<<<blocks, 256, 0, stream>>>(
      tg, sg, am, acc, repl,
      subs[0][0], subs[0][1], subs[1][0], subs[1][1], subs[2][0], subs[2][1],
      N, total_waves);
  finalize_kernel<<<1, 64, 0, stream>>>(acc, repl, (float*)d_out);
}

// Round 7
// 52.211 us; speedup vs baseline: 6.0954x; 1.1621x over previous
//
#include <hip/hip_runtime.h>
#include <stdint.h>

#define ET 128
#define ES 16
#define ACC_STRIDE 258   // doubles per replica slot
#define ACC_USED 34      // [0]=sum_w [1]=sum_klw [2..17]=t_counts [18..33]=s_counts
#define MAX_REPL 64

__host__ __device__ inline uint32_t rotl32(uint32_t x, int r) {
#ifdef __HIP_DEVICE_COMPILE__
  return __builtin_amdgcn_alignbit(x, x, (uint32_t)(32 - r));  // 1 instr guaranteed
#else
  return (x << r) | (x >> (32 - r));
#endif
}

__host__ __device__ inline void tf2x32(uint32_t k0, uint32_t k1,
                                       uint32_t& x0, uint32_t& x1) {
  uint32_t ks2 = k0 ^ k1 ^ 0x1BD11BDAu;
  x0 += k0; x1 += k1;
#define TF_ROT(r) { x0 += x1; x1 = rotl32(x1, r); x1 ^= x0; }
  TF_ROT(13) TF_ROT(15) TF_ROT(26) TF_ROT(6)
  x0 += k1;  x1 += ks2 + 1u;
  TF_ROT(17) TF_ROT(29) TF_ROT(16) TF_ROT(24)
  x0 += ks2; x1 += k0 + 2u;
  TF_ROT(13) TF_ROT(15) TF_ROT(26) TF_ROT(6)
  x0 += k0;  x1 += k1 + 3u;
  TF_ROT(17) TF_ROT(29) TF_ROT(16) TF_ROT(24)
  x0 += k1;  x1 += ks2 + 4u;
  TF_ROT(13) TF_ROT(15) TF_ROT(26) TF_ROT(6)
  x0 += ks2; x1 += k0 + 5u;
#undef TF_ROT
}

// partitionable threefry: uniform(0,1) for flat index j under subkey s
__device__ inline float unif01(uint32_t s0, uint32_t s1, uint32_t j) {
  uint32_t x0 = 0u, x1 = j;
  tf2x32(s0, s1, x0, x1);
  uint32_t bits = x0 ^ x1;
  float f = __uint_as_float((bits >> 9) | 0x3F800000u) - 1.0f;
  const float TINY = 1.17549435e-38f;
  return fmaxf(TINY, f + TINY);
}

// 16 lanes/token, 8 experts/lane, 4 tokens/wave.
// Winner = argmin_e( -log(u_e)/p_e )  (exponential race == gumbel argmax).
// Positive scores => f32 bits order-preserving; (bits<<32)|idx u64 min
// reduce gives lowest-index tie-break (matches jnp.argmax first-hit).
__launch_bounds__(256)
__global__ void sample_kernel(const float* __restrict__ tg,
                              const float* __restrict__ sg,
                              const int* __restrict__ am,
                              double* __restrict__ acc,
                              unsigned int* __restrict__ done,
                              float* __restrict__ out,
                              int repl,
                              uint32_t s00, uint32_t s01,
                              uint32_t s10, uint32_t s11,
                              uint32_t s20, uint32_t s21,
                              int N, int total_waves) {
  __shared__ float lds_t[ES], lds_s[ES];
  __shared__ float lds_w[4], lds_kl[4];
  __shared__ int lds_last;
  __shared__ double tot[ACC_USED];
  if (threadIdx.x < ES) { lds_t[threadIdx.x] = 0.f; lds_s[threadIdx.x] = 0.f; }
  __syncthreads();

  const int wslot = threadIdx.x >> 6;
  const int wid = blockIdx.x * 4 + wslot;
  const int lane = threadIdx.x & 63;
  const int gl = lane & 15;        // lane within 16-lane token group
  const int gbase = lane & 0x30;   // first lane of this group
  const int stride = total_waves * 4;

  float sum_w = 0.f, sum_kl = 0.f;

#define LOADT(BASE, P, SGV, VM)                                              \
  {                                                                          \
    int nr_ = (BASE) + (lane >> 4);                                          \
    int ok_ = (nr_ < N);                                                     \
    int n_ = ok_ ? nr_ : (N - 1);                                            \
    const float4* r4_ = (const float4*)(tg + (size_t)n_ * ET + gl * 8);      \
    float4 aa_ = r4_[0], bb_ = r4_[1];                                       \
    P[0] = aa_.x; P[1] = aa_.y; P[2] = aa_.z; P[3] = aa_.w;                  \
    P[4] = bb_.x; P[5] = bb_.y; P[6] = bb_.z; P[7] = bb_.w;                  \
    SGV = sg[(size_t)n_ * ES + gl];                                          \
    VM = ok_ ? (float)am[n_] : 0.f;                                          \
  }

#define STEP(KA, KB, LAST)                                                   \
  {                                                                          \
    float e[8];                                                              \
    _Pragma("unroll")                                                        \
    for (int q = 0; q < 8; ++q)                                              \
      e[q] = -__logf(unif01(KA, KB, jb + (uint32_t)q)) * inv[q];             \
    unsigned long long key = ~0ull, ko;                                      \
    _Pragma("unroll")                                                        \
    for (int q = 0; q < 8; ++q) {                                            \
      ko = ((unsigned long long)__float_as_uint(e[q]) << 32)                 \
           | (uint32_t)(ebase + q);                                          \
      if (ko < key) key = ko;                                                \
    }                                                                        \
    ko = __shfl_xor(key, 1); if (ko < key) key = ko;                         \
    ko = __shfl_xor(key, 2); if (ko < key) key = ko;                         \
    ko = __shfl_xor(key, 4); if (ko < key) key = ko;                         \
    ko = __shfl_xor(key, 8); if (ko < key) key = ko;                         \
    const int bi = (int)(key & 0xFFu);                                       \
    const int wl = bi >> 3, wslt = bi & 7;                                   \
    float pw = p[0];                                                         \
    _Pragma("unroll")                                                        \
    for (int q = 1; q < 8; ++q) pw = (wslt == q) ? p[q] : pw;                \
    float w_abs = __shfl(pw, gbase | wl);                                    \
    float sgkl = __shfl(sgv, gbase | wl);                                    \
    float sgcv = __shfl(sgv, gbase | (bi & 15));                             \
    float wsv = w_abs * __frcp_rn(t) * vm;                                   \
    const bool lead = (gl == 0);                                             \
    sum_w += lead ? wsv : 0.f;                                               \
    float klt = ((bi & 7) == 0) ? (-__logf(sgkl)) * wsv : 0.f;               \
    sum_kl += lead ? klt : 0.f;                                              \
    if (lead && bi < ES) {                                                   \
      atomicAdd(&lds_t[bi], wsv);                                            \
      atomicAdd(&lds_s[bi], sgcv * vm);                                      \
    }                                                                        \
    if (!(LAST)) {                                                           \
      const bool mt = (gl == wl);                                            \
      _Pragma("unroll")                                                      \
      for (int q = 0; q < 8; ++q) {                                          \
        bool hit = mt && (wslt == q);                                        \
        p[q] = hit ? p[q] * 0.5f : p[q];                                     \
        inv[q] = hit ? inv[q] * 2.0f : inv[q];                               \
      }                                                                      \
      t -= 0.5f * w_abs;                                                     \
    }                                                                        \
  }

  float p[8], sgv = 0.f, vm = 0.f;
  const int base0 = wid * 4;
  if (base0 < N) LOADT(base0, p, sgv, vm);

  for (int base = base0; base < N; base += stride) {
    // software pipeline: prefetch next tile before computing current
    const int nxt = base + stride;
    float pn[8] = {0, 0, 0, 0, 0, 0, 0, 0};
    float sgn = 0.f, vmn = 0.f;
    if (nxt < N) LOADT(nxt, pn, sgn, vmn);

    {
      int nr = base + (lane >> 4);
      int n_ = (nr < N) ? nr : (N - 1);
      const uint32_t jb = (uint32_t)n_ * ET + (uint32_t)(gl * 8);
      const int ebase = gl * 8;
      float inv[8];
#pragma unroll
      for (int q = 0; q < 8; ++q) inv[q] = __frcp_rn(p[q]);
      float t = 1.0f;
      STEP(s00, s01, 0)
      STEP(s10, s11, 0)
      STEP(s20, s21, 1)
    }

#pragma unroll
    for (int q = 0; q < 8; ++q) p[q] = pn[q];
    sgv = sgn; vm = vmn;
  }
#undef STEP
#undef LOADT

#pragma unroll
  for (int off = 32; off; off >>= 1) {
    sum_w += __shfl_xor(sum_w, off);
    sum_kl += __shfl_xor(sum_kl, off);
  }
  if (lane == 0) { lds_w[wslot] = sum_w; lds_kl[wslot] = sum_kl; }
  __syncthreads();

  double* slot = acc + (size_t)(blockIdx.x % repl) * ACC_STRIDE;
  if (threadIdx.x == 0) {
    atomicAdd(&slot[0], (double)(lds_w[0] + lds_w[1] + lds_w[2] + lds_w[3]));
    atomicAdd(&slot[1], (double)(lds_kl[0] + lds_kl[1] + lds_kl[2] + lds_kl[3]));
  }
  if (threadIdx.x < ES) {
    atomicAdd(&slot[2 + threadIdx.x], (double)lds_t[threadIdx.x]);
    atomicAdd(&slot[2 + ES + threadIdx.x], (double)lds_s[threadIdx.x]);
  }

  // ---- last-block finalize (fused; saves a kernel launch) ----
  if (threadIdx.x == 0) {
    __threadfence();
    unsigned prev = atomicAdd(done, 1u);
    lds_last = (prev == (unsigned)(gridDim.x - 1)) ? 1 : 0;
  }
  __syncthreads();
  if (!lds_last) return;

  const int tid = threadIdx.x;
  if (tid < ACC_USED) tot[tid] = 0.0;
  __syncthreads();
  // agent-scope loads: bypass potentially-stale per-XCD cached copies
  for (int idx = tid; idx < repl * ACC_USED; idx += 256) {
    int r = idx / ACC_USED, f = idx - r * ACC_USED;
    double v = __hip_atomic_load(&acc[(size_t)r * ACC_STRIDE + f],
                                 __ATOMIC_RELAXED, __HIP_MEMORY_SCOPE_AGENT);
    atomicAdd(&tot[f], v);
  }
  __syncthreads();

  const double EPSD = 1e-8;
  double tv = (tid < ES) ? tot[2 + tid] : 0.0;
  double sv = (tid < ES) ? tot[2 + ES + tid] : 0.0;
  double tsum = tv, ssum = sv;
#pragma unroll
  for (int off = 8; off; off >>= 1) {
    tsum += __shfl_xor(tsum, off);
    ssum += __shfl_xor(ssum, off);
  }
  double ta = tv / tsum + EPSD;
  double sa = sv / ssum + EPSD;
  double ta2 = (tid < ES) ? ta : 0.0;
  double sa2 = (tid < ES) ? sa : 0.0;
#pragma unroll
  for (int off = 8; off; off >>= 1) {
    ta2 += __shfl_xor(ta2, off);
    sa2 += __shfl_xor(sa2, off);
  }
  ta2 += (double)(ET - ES) * EPSD;   // 112 zero bins contribute EPS each
  sa2 += (double)(ET - ES) * EPSD;
  double tn = ta / ta2, sn = sa / sa2;
  double ci = (tid < ES) ? tn * (log(tn) - log(sn)) : 0.0;
#pragma unroll
  for (int off = 8; off; off >>= 1) ci += __shfl_xor(ci, off);

  if (tid == 0) {
    double ta0 = EPSD / ta2, sa0 = EPSD / sa2;
    double cov = ci + (double)(ET - ES) * ta0 * (log(ta0) - log(sa0));
    cov /= (double)ET;
    double feat = tot[1] / fmax(tot[0], EPSD);
    out[0] = (float)(feat + 0.5 * cov);
  }
}

extern "C" void kernel_launch(void* const* d_in, const int* in_sizes, int n_in,
                              void* d_out, int out_size, void* d_ws, size_t ws_size,
                              hipStream_t stream) {
  const float* tg = (const float*)d_in[0];
  const float* sg = (const float*)d_in[1];
  const int*   am = (const int*)d_in[4];
  const int N = in_sizes[4];  // B*S tokens

  // key chain: key = jax.random.key(42); per step foldlike split (partitionable)
  uint32_t key0 = 0u, key1 = 42u;
  uint32_t subs[3][2];
  for (int k = 0; k < 3; ++k) {
    uint32_t a0 = 0u, a1 = 0u; tf2x32(key0, key1, a0, a1);  // new key
    uint32_t b0 = 0u, b1 = 1u; tf2x32(key0, key1, b0, b1);  // subkey
    subs[k][0] = b0; subs[k][1] = b1;
    key0 = a0; key1 = a1;
  }

  int repl = (int)((ws_size - 256) / (ACC_STRIDE * sizeof(double)));
  if (repl > MAX_REPL) repl = MAX_REPL;
  if (repl < 1) repl = 1;

  double* acc = (double*)d_ws;
  unsigned int* done = (unsigned int*)((char*)d_ws + (size_t)repl * ACC_STRIDE * sizeof(double));
  // zero replica slots + done counter in one memset
  hipMemsetAsync(d_ws, 0, (size_t)repl * ACC_STRIDE * sizeof(double) + 64, stream);

  // 4 waves/block, 4 tokens/wave-iter; ~2 grid-stride iterations for pipelining
  int blocks = (N + 31) / 32;
  if (blocks > 2048) blocks = 2048;
  if (blocks < 1) blocks = 1;
  const int total_waves = blocks * 4;

  sample_kernel<<<blocks, 256, 0, stream>>>(
      tg, sg, am, acc, done, (float*)d_out, repl,
      subs[0][0], subs[0][1], subs[1][0], subs[1][1], subs[2][0], subs[2][1],
      N, total_waves);
}

// Round 8
// 50.078 us; speedup vs baseline: 6.3550x; 1.0426x over previous
//
#include <hip/hip_runtime.h>
#include <stdint.h>

#define ET 128
#define ES 16
#define ACC_STRIDE 258   // doubles per replica slot
#define ACC_USED 34      // [0]=sum_w [1]=sum_klw [2..17]=t_counts [18..33]=s_counts
#define MAX_REPL 64

__host__ __device__ inline uint32_t rotl32(uint32_t x, int r) {
#ifdef __HIP_DEVICE_COMPILE__
  return __builtin_amdgcn_alignbit(x, x, (uint32_t)(32 - r));  // 1 instr
#else
  return (x << r) | (x >> (32 - r));
#endif
}

__host__ __device__ inline void tf2x32(uint32_t k0, uint32_t k1,
                                       uint32_t& x0, uint32_t& x1) {
  uint32_t ks2 = k0 ^ k1 ^ 0x1BD11BDAu;
  x0 += k0; x1 += k1;
#define TF_ROT(r) { x0 += x1; x1 = rotl32(x1, r); x1 ^= x0; }
  TF_ROT(13) TF_ROT(15) TF_ROT(26) TF_ROT(6)
  x0 += k1;  x1 += ks2 + 1u;
  TF_ROT(17) TF_ROT(29) TF_ROT(16) TF_ROT(24)
  x0 += ks2; x1 += k0 + 2u;
  TF_ROT(13) TF_ROT(15) TF_ROT(26) TF_ROT(6)
  x0 += k0;  x1 += k1 + 3u;
  TF_ROT(17) TF_ROT(29) TF_ROT(16) TF_ROT(24)
  x0 += k1;  x1 += ks2 + 4u;
  TF_ROT(13) TF_ROT(15) TF_ROT(26) TF_ROT(6)
  x0 += ks2; x1 += k0 + 5u;
#undef TF_ROT
}

// partitionable threefry: uniform(0,1) for flat index j under subkey s
__device__ inline float unif01(uint32_t s0, uint32_t s1, uint32_t j) {
  uint32_t x0 = 0u, x1 = j;
  tf2x32(s0, s1, x0, x1);
  uint32_t bits = x0 ^ x1;
  float f = __uint_as_float((bits >> 9) | 0x3F800000u) - 1.0f;
  const float TINY = 1.17549435e-38f;
  return fmaxf(TINY, f + TINY);
}

__device__ inline float fastrcp(float x) { return __builtin_amdgcn_rcpf(x); }

// DPP lane-rotate within 16-lane row (gfx9: row = 16 lanes)
template <int CTRL>
__device__ inline uint32_t dpp32(uint32_t v) {
  return (uint32_t)__builtin_amdgcn_update_dpp((int)v, (int)v, CTRL, 0xF, 0xF,
                                               false);
}

// 16 lanes/token, 8 experts/lane, 4 tokens/wave.
// Winner = argmin_e( -log(u_e)/p_e )  (exponential race == gumbel argmax).
// Positive scores => f32 bits order-preserving; (bits<<32)|idx u64 min
// reduce (DPP row_ror, no LDS) gives lowest-index tie-break.
__launch_bounds__(256)
__global__ void sample_kernel(const float* __restrict__ tg,
                              const float* __restrict__ sg,
                              const int* __restrict__ am,
                              double* __restrict__ acc,
                              unsigned int* __restrict__ done,
                              float* __restrict__ out,
                              int repl,
                              uint32_t s00, uint32_t s01,
                              uint32_t s10, uint32_t s11,
                              uint32_t s20, uint32_t s21,
                              int N, int total_waves) {
  __shared__ float lds_t[ES], lds_s[ES];
  __shared__ float lds_w[4], lds_kl[4];
  __shared__ int lds_last;
  __shared__ double tot[ACC_USED];
  if (threadIdx.x < ES) { lds_t[threadIdx.x] = 0.f; lds_s[threadIdx.x] = 0.f; }
  __syncthreads();

  const int wslot = threadIdx.x >> 6;
  const int wid = blockIdx.x * 4 + wslot;
  const int lane = threadIdx.x & 63;
  const int gl = lane & 15;        // lane within 16-lane token group
  const int gbase = lane & 0x30;   // first lane of this group
  const int stride = total_waves * 4;

  float sum_w = 0.f, sum_kl = 0.f;

#define LOADT(BASE, P, SGV, VM)                                              \
  {                                                                          \
    int nr_ = (BASE) + (lane >> 4);                                          \
    int ok_ = (nr_ < N);                                                     \
    int n_ = ok_ ? nr_ : (N - 1);                                            \
    const float4* r4_ = (const float4*)(tg + (size_t)n_ * ET + gl * 8);      \
    float4 aa_ = r4_[0], bb_ = r4_[1];                                       \
    P[0] = aa_.x; P[1] = aa_.y; P[2] = aa_.z; P[3] = aa_.w;                  \
    P[4] = bb_.x; P[5] = bb_.y; P[6] = bb_.z; P[7] = bb_.w;                  \
    SGV = sg[(size_t)n_ * ES + gl];                                          \
    VM = ok_ ? (float)am[n_] : 0.f;                                          \
  }

#define DPP_MIN_STAGE(CTRL)                                                  \
  {                                                                          \
    uint32_t plo = dpp32<CTRL>(klo), phi = dpp32<CTRL>(khi);                 \
    unsigned long long pk = ((unsigned long long)phi << 32) | plo;           \
    unsigned long long ck = ((unsigned long long)khi << 32) | klo;           \
    if (pk < ck) { klo = plo; khi = phi; }                                   \
  }

#define STEP(KA, KB, LAST)                                                   \
  {                                                                          \
    float e[8];                                                              \
    _Pragma("unroll")                                                        \
    for (int q = 0; q < 8; ++q)                                              \
      e[q] = -__logf(unif01(KA, KB, jb + (uint32_t)q)) * inv[q];             \
    uint32_t khi = __float_as_uint(e[0]), klo = (uint32_t)(ebase + 0);       \
    _Pragma("unroll")                                                        \
    for (int q = 1; q < 8; ++q) {                                            \
      uint32_t h = __float_as_uint(e[q]);                                    \
      bool tk = (h < khi);                                                   \
      klo = tk ? (uint32_t)(ebase + q) : klo;                                \
      khi = tk ? h : khi;                                                    \
    }                                                                        \
    DPP_MIN_STAGE(0x128)  /* row_ror:8 */                                    \
    DPP_MIN_STAGE(0x124)  /* row_ror:4 */                                    \
    DPP_MIN_STAGE(0x122)  /* row_ror:2 */                                    \
    DPP_MIN_STAGE(0x121)  /* row_ror:1 */                                    \
    const int bi = (int)(klo & 0xFFu);                                       \
    const int wl = bi >> 3, wslt = bi & 7;                                   \
    float pw = p[0];                                                         \
    _Pragma("unroll")                                                        \
    for (int q = 1; q < 8; ++q) pw = (wslt == q) ? p[q] : pw;                \
    float w_abs = __shfl(pw, gbase | wl);                                    \
    float sgkl = __shfl(sgv, gbase | wl);                                    \
    float sgcv = __shfl(sgv, gbase | (bi & 15));                             \
    float wsv = w_abs * fastrcp(t) * vm;                                     \
    const bool lead = (gl == 0);                                             \
    sum_w += lead ? wsv : 0.f;                                               \
    float klt = ((bi & 7) == 0) ? (-__logf(sgkl)) * wsv : 0.f;               \
    sum_kl += lead ? klt : 0.f;                                              \
    if (lead && bi < ES) {                                                   \
      atomicAdd(&lds_t[bi], wsv);                                            \
      atomicAdd(&lds_s[bi], sgcv * vm);                                      \
    }                                                                        \
    if (!(LAST)) {                                                           \
      const bool mt = (gl == wl);                                            \
      _Pragma("unroll")                                                      \
      for (int q = 0; q < 8; ++q) {                                          \
        bool hit = mt && (wslt == q);                                        \
        p[q] = hit ? p[q] * 0.5f : p[q];                                     \
        inv[q] = hit ? inv[q] * 2.0f : inv[q];                               \
      }                                                                      \
      t -= 0.5f * w_abs;                                                     \
    }                                                                        \
  }

  float p[8], sgv = 0.f, vm = 0.f;
  const int base0 = wid * 4;
  if (base0 < N) LOADT(base0, p, sgv, vm);

  for (int base = base0; base < N; base += stride) {
    // software pipeline: prefetch next tile before computing current
    const int nxt = base + stride;
    float pn[8] = {0, 0, 0, 0, 0, 0, 0, 0};
    float sgn = 0.f, vmn = 0.f;
    if (nxt < N) LOADT(nxt, pn, sgn, vmn);

    {
      int nr = base + (lane >> 4);
      int n_ = (nr < N) ? nr : (N - 1);
      const uint32_t jb = (uint32_t)n_ * ET + (uint32_t)(gl * 8);
      const int ebase = gl * 8;
      float inv[8];
#pragma unroll
      for (int q = 0; q < 8; ++q) inv[q] = fastrcp(p[q]);
      float t = 1.0f;
      STEP(s00, s01, 0)
      STEP(s10, s11, 0)
      STEP(s20, s21, 1)
    }

#pragma unroll
    for (int q = 0; q < 8; ++q) p[q] = pn[q];
    sgv = sgn; vm = vmn;
  }
#undef STEP
#undef DPP_MIN_STAGE
#undef LOADT

#pragma unroll
  for (int off = 32; off; off >>= 1) {
    sum_w += __shfl_xor(sum_w, off);
    sum_kl += __shfl_xor(sum_kl, off);
  }
  if (lane == 0) { lds_w[wslot] = sum_w; lds_kl[wslot] = sum_kl; }
  __syncthreads();

  double* slot = acc + (size_t)(blockIdx.x % repl) * ACC_STRIDE;
  if (threadIdx.x == 0) {
    atomicAdd(&slot[0], (double)(lds_w[0] + lds_w[1] + lds_w[2] + lds_w[3]));
    atomicAdd(&slot[1], (double)(lds_kl[0] + lds_kl[1] + lds_kl[2] + lds_kl[3]));
  }
  if (threadIdx.x < ES) {
    atomicAdd(&slot[2 + threadIdx.x], (double)lds_t[threadIdx.x]);
    atomicAdd(&slot[2 + ES + threadIdx.x], (double)lds_s[threadIdx.x]);
  }

  // ---- last-block finalize (fused) ----
  if (threadIdx.x == 0) {
    __threadfence();
    unsigned prev = atomicAdd(done, 1u);
    lds_last = (prev == (unsigned)(gridDim.x - 1)) ? 1 : 0;
  }
  __syncthreads();
  if (!lds_last) return;

  const int tid = threadIdx.x;
  if (tid < ACC_USED) tot[tid] = 0.0;
  __syncthreads();
  for (int idx = tid; idx < repl * ACC_USED; idx += 256) {
    int r = idx / ACC_USED, f = idx - r * ACC_USED;
    double v = __hip_atomic_load(&acc[(size_t)r * ACC_STRIDE + f],
                                 __ATOMIC_RELAXED, __HIP_MEMORY_SCOPE_AGENT);
    atomicAdd(&tot[f], v);
  }
  __syncthreads();

  const double EPSD = 1e-8;
  double tv = (tid < ES) ? tot[2 + tid] : 0.0;
  double sv = (tid < ES) ? tot[2 + ES + tid] : 0.0;
  double tsum = tv, ssum = sv;
#pragma unroll
  for (int off = 8; off; off >>= 1) {
    tsum += __shfl_xor(tsum, off);
    ssum += __shfl_xor(ssum, off);
  }
  double ta = tv / tsum + EPSD;
  double sa = sv / ssum + EPSD;
  double ta2 = (tid < ES) ? ta : 0.0;
  double sa2 = (tid < ES) ? sa : 0.0;
#pragma unroll
  for (int off = 8; off; off >>= 1) {
    ta2 += __shfl_xor(ta2, off);
    sa2 += __shfl_xor(sa2, off);
  }
  ta2 += (double)(ET - ES) * EPSD;   // 112 zero bins contribute EPS each
  sa2 += (double)(ET - ES) * EPSD;
  double tn = ta / ta2, sn = sa / sa2;
  double ci = (tid < ES) ? tn * (log(tn) - log(sn)) : 0.0;
#pragma unroll
  for (int off = 8; off; off >>= 1) ci += __shfl_xor(ci, off);

  if (tid == 0) {
    double ta0 = EPSD / ta2, sa0 = EPSD / sa2;
    double cov = ci + (double)(ET - ES) * ta0 * (log(ta0) - log(sa0));
    cov /= (double)ET;
    double feat = tot[1] / fmax(tot[0], EPSD);
    out[0] = (float)(feat + 0.5 * cov);
  }
}

extern "C" void kernel_launch(void* const* d_in, const int* in_sizes, int n_in,
                              void* d_out, int out_size, void* d_ws, size_t ws_size,
                              hipStream_t stream) {
  const float* tg = (const float*)d_in[0];
  const float* sg = (const float*)d_in[1];
  const int*   am = (const int*)d_in[4];
  const int N = in_sizes[4];  // B*S tokens

  // key chain: key = jax.random.key(42); per step foldlike split (partitionable)
  uint32_t key0 = 0u, key1 = 42u;
  uint32_t subs[3][2];
  for (int k = 0; k < 3; ++k) {
    uint32_t a0 = 0u, a1 = 0u; tf2x32(key0, key1, a0, a1);  // new key
    uint32_t b0 = 0u, b1 = 1u; tf2x32(key0, key1, b0, b1);  // subkey
    subs[k][0] = b0; subs[k][1] = b1;
    key0 = a0; key1 = a1;
  }

  int repl = (int)((ws_size - 256) / (ACC_STRIDE * sizeof(double)));
  if (repl > MAX_REPL) repl = MAX_REPL;
  if (repl < 1) repl = 1;

  double* acc = (double*)d_ws;
  unsigned int* done = (unsigned int*)((char*)d_ws + (size_t)repl * ACC_STRIDE * sizeof(double));
  hipMemsetAsync(d_ws, 0, (size_t)repl * ACC_STRIDE * sizeof(double) + 64, stream);

  // 4 waves/block, 4 tokens/wave-iter; ~2 grid-stride iterations for pipelining
  int blocks = (N + 31) / 32;
  if (blocks > 2048) blocks = 2048;
  if (blocks < 1) blocks = 1;
  const int total_waves = blocks * 4;

  sample_kernel<<<blocks, 256, 0, stream>>>(
      tg, sg, am, acc, done, (float*)d_out, repl,
      subs[0][0], subs[0][1], subs[1][0], subs[1][1], subs[2][0], subs[2][1],
      N, total_waves);
}